// Round 26
// baseline (128.717 us; speedup 1.0000x reference)
//
#include <hip/hip_runtime.h>

#define N_NODES 100000
#define N_EDGES 1600000
#define IN_CH 64
#define HID_CH 128

#define BIN_SZ 256                                     // nodes per bin
#define BIN_BITS 8
#define NBINS ((N_NODES + BIN_SZ - 1) / BIN_SZ)        // 391 bins
#define BIN_CAP 4864                                   // fixed region per bin
#define SEPB 4096                                      // edges per stage block
#define STAGE_BLOCKS ((N_EDGES + SEPB - 1) / SEPB)     // 391
#define EPT 16                                         // edges per thread (SEPB/256)
#define CVT_BLOCKS 768                                 // dedicated h->bf16 blocks
#define BIN_CACHE 8192                                 // LDS edge cache per bin

typedef __attribute__((ext_vector_type(8))) short bf16x8;  // 8 bf16 = 4 VGPR
typedef __attribute__((ext_vector_type(4))) float f32x4;

static __device__ __forceinline__ unsigned short f2bf(float f) {
    union { float f; unsigned int u; } v; v.f = f;
    const unsigned int u = v.u;
    return (unsigned short)((u + 0x7FFFu + ((u >> 16) & 1u)) >> 16);  // RNE
}

#define UNPACK_ADD(A, V) do {                                         \
    union { unsigned int u; float f; } lo_, hi_;                      \
    _Pragma("unroll")                                                 \
    for (int j_ = 0; j_ < 4; ++j_) {                                  \
        const unsigned int w_ = (&(V).x)[j_];                         \
        lo_.u = w_ << 16;         A[2 * j_] += lo_.f;                 \
        hi_.u = w_ & 0xFFFF0000u; A[2 * j_ + 1] += hi_.f;             \
    } } while (0)

// ---------------- stage: histogram-free partition, single ei read ---------
__global__ __launch_bounds__(256) void sage_stage(
    const int* __restrict__ ei, int* __restrict__ bin_cursor,
    int* __restrict__ stage)
{
    __shared__ int s_cnt[NBINS];
    __shared__ int s_base[NBINS];
    const int t = threadIdx.x;
    for (int i = t; i < NBINS; i += 256) s_cnt[i] = 0;
    __syncthreads();
    const int e0 = blockIdx.x * SEPB;
    int pk[EPT];
    short bin[EPT];
#pragma unroll
    for (int k = 0; k < EPT; ++k) {
        const int e = e0 + k * 256 + t;
        if (e < N_EDGES) {
            const int dst = ei[e];
            const int src = ei[N_EDGES + e];
            bin[k] = (short)(dst >> BIN_BITS);
            pk[k] = ((dst & (BIN_SZ - 1)) << 17) | src;
            atomicAdd(&s_cnt[bin[k]], 1);
        } else bin[k] = -1;
    }
    __syncthreads();
    for (int i = t; i < NBINS; i += 256) {
        const int c = s_cnt[i];
        s_base[i] = (c > 0) ? (i * BIN_CAP + atomicAdd(&bin_cursor[i], c)) : 0;
        s_cnt[i] = 0;
    }
    __syncthreads();
#pragma unroll
    for (int k = 0; k < EPT; ++k) {
        if (bin[k] >= 0) {
            const int bb = bin[k];
            const int p = s_base[bb] + atomicAdd(&s_cnt[bb], 1);
            if (p < (bb + 1) * BIN_CAP)
                stage[p] = pk[k];
        }
    }
}

// ---------------- bucket2: CSR finalize + within-bin degree sort ----------
// Blocks [0,NBINS): per-bin CSR finalize + counting sort of the bin's nodes
// by degree -> perm (equal-degree m-tiles; all accesses stay in the bin's
// 256-node window, preserving locality). First 64 blocks also pack Bt.
// Blocks [NBINS,NBINS+CVT_BLOCKS): h -> bf16 conversion (concurrent).
__global__ __launch_bounds__(256) void sage_bucket2(
    const int* __restrict__ stage, const int* __restrict__ bin_cursor,
    const float* __restrict__ Wl, const float* __restrict__ Wr,
    const float* __restrict__ h, unsigned short* __restrict__ hb,
    unsigned short* __restrict__ Bt, int* __restrict__ node_cnt,
    int* __restrict__ node_start, int* __restrict__ bucket,
    int* __restrict__ perm)
{
    const int b = blockIdx.x;
    const int t = threadIdx.x;

    if (b >= NBINS) {
        const int n4 = N_NODES * IN_CH / 4;
        for (int i = (b - NBINS) * 256 + t; i < n4; i += CVT_BLOCKS * 256) {
            const float4 v = reinterpret_cast<const float4*>(h)[i];
            ushort4 o;
            o.x = f2bf(v.x); o.y = f2bf(v.y); o.z = f2bf(v.z); o.w = f2bf(v.w);
            reinterpret_cast<ushort4*>(hb)[i] = o;
        }
        return;
    }

    __shared__ int s_cnt[BIN_SZ];
    __shared__ int s_off[BIN_SZ];
    __shared__ int s_cur[BIN_SZ];
    __shared__ int s_edges[BIN_CACHE];
    __shared__ int s_dh[64];
    __shared__ int s_dscan[64];
    __shared__ int s_dcur[64];
    // fused Bt pack: first 64 blocks cover 128x128
    {
        const int wi = b * 256 + t;
        if (wi < HID_CH * HID_CH) {
            const int n = wi >> 7, k = wi & 127;
            const float v = (k < 64) ? Wl[k * HID_CH + n] : Wr[(k - 64) * HID_CH + n];
            Bt[wi] = f2bf(v);
        }
    }
    s_cnt[t] = 0; s_cur[t] = 0;
    if (t < 64) { s_dh[t] = 0; s_dcur[t] = 0; }
    __syncthreads();
    const int start = b * BIN_CAP;
    int len = bin_cursor[b];
    len = (len > BIN_CAP) ? BIN_CAP : len;
    const bool cached = (len <= BIN_CACHE);
    if (cached) {
        for (int i = t; i < len; i += 256) {
            const int p = stage[start + i];
            s_edges[i] = p;
            atomicAdd(&s_cnt[p >> 17], 1);
        }
    } else {
        for (int i = t; i < len; i += 256)
            atomicAdd(&s_cnt[stage[start + i] >> 17], 1);
    }
    __syncthreads();
    const int v = s_cnt[t];
    s_off[t] = v;
    __syncthreads();
    for (int off = 1; off < 256; off <<= 1) {
        const int a = (t >= off) ? s_off[t - off] : 0;
        __syncthreads();
        s_off[t] += a;
        __syncthreads();
    }
    const int excl = s_off[t] - v;
    s_off[t] = excl;
    __syncthreads();
    const int node = (b << BIN_BITS) + t;
    int cls = -1;
    if (node < N_NODES) {
        node_cnt[node] = v;
        node_start[node] = start + excl;
        cls = (v > 63) ? 63 : v;
        atomicAdd(&s_dh[cls], 1);
    }
    __syncthreads();
    // inclusive scan of 64 degree-class counts (ALL threads hit barriers)
    if (t < 64) s_dscan[t] = s_dh[t];
    __syncthreads();
    for (int off = 1; off < 64; off <<= 1) {
        int a = 0;
        if (t < 64 && t >= off) a = s_dscan[t - off];
        __syncthreads();
        if (t < 64) s_dscan[t] += a;
        __syncthreads();
    }
    if (cls >= 0) {
        const int base = (cls > 0) ? s_dscan[cls - 1] : 0;
        const int pos = base + atomicAdd(&s_dcur[cls], 1);
        perm[(b << BIN_BITS) + pos] = node;
    }
    if (cached) {
        for (int i = t; i < len; i += 256) {
            const int p = s_edges[i];
            const int l = p >> 17;
            bucket[start + s_off[l] + atomicAdd(&s_cur[l], 1)] = p & 0x1FFFF;
        }
    } else {
        for (int i = t; i < len; i += 256) {
            const int p = stage[start + i];
            const int l = p >> 17;
            bucket[start + s_off[l] + atomicAdd(&s_cur[l], 1)] = p & 0x1FFFF;
        }
    }
}

// ---------------- fused gather+mean+MFMA (degree-uniform tiles) -----------
// One block = 16 perm-slots of one bin (near-equal degree -> maxd ~ avg,
// minimal barrier tail), 256 threads = 4 waves. Structure otherwise =
// round-12 floor variant. All accesses stay within the bin's 256-node window.
__global__ __launch_bounds__(256) void sage_gmfma(
    const int* __restrict__ node_cnt, const int* __restrict__ node_start,
    const int* __restrict__ bucket, const unsigned short* __restrict__ hb,
    const unsigned short* __restrict__ Bt, const float* __restrict__ bias,
    const int* __restrict__ perm, float* __restrict__ out)
{
    __shared__ unsigned short s_mean[16][72];  // padded: 144B row stride
    const int t = threadIdx.x;
    const int w = t >> 6;           // wave 0..3
    const int lane = t & 63;
    const int sub = lane >> 3;      // edge slot 0..7
    const int c8 = lane & 7;        // 8-channel group within row
    const int bin = blockIdx.x >> 4;
    const int base = (bin << BIN_BITS) + (blockIdx.x & 15) * 16;  // perm base

    // ---- phase 1: interleaved gather for the wave's 4 nodes ----
    int d_[4], st_[4];
#pragma unroll
    for (int nn = 0; nn < 4; ++nn) {
        const int node = perm[base + w * 4 + nn];
        d_[nn] = node_cnt[node];
        st_[nn] = node_start[node];
    }
    int maxd = d_[0];
#pragma unroll
    for (int nn = 1; nn < 4; ++nn) maxd = (d_[nn] > maxd) ? d_[nn] : maxd;

    float a0[8] = {0.f,0.f,0.f,0.f,0.f,0.f,0.f,0.f};
    float a1[8] = {0.f,0.f,0.f,0.f,0.f,0.f,0.f,0.f};
    float a2[8] = {0.f,0.f,0.f,0.f,0.f,0.f,0.f,0.f};
    float a3[8] = {0.f,0.f,0.f,0.f,0.f,0.f,0.f,0.f};

    for (int g = 0; g < maxd; g += 8) {
        const int e = g + sub;
        int s0 = -1, s1 = -1, s2 = -1, s3 = -1;
        if (e < d_[0]) s0 = bucket[st_[0] + e];
        if (e < d_[1]) s1 = bucket[st_[1] + e];
        if (e < d_[2]) s2 = bucket[st_[2] + e];
        if (e < d_[3]) s3 = bucket[st_[3] + e];
        if (s0 >= 0) {
            const uint4 v = *reinterpret_cast<const uint4*>(hb + (size_t)s0 * IN_CH + c8 * 8);
            UNPACK_ADD(a0, v);
        }
        if (s1 >= 0) {
            const uint4 v = *reinterpret_cast<const uint4*>(hb + (size_t)s1 * IN_CH + c8 * 8);
            UNPACK_ADD(a1, v);
        }
        if (s2 >= 0) {
            const uint4 v = *reinterpret_cast<const uint4*>(hb + (size_t)s2 * IN_CH + c8 * 8);
            UNPACK_ADD(a2, v);
        }
        if (s3 >= 0) {
            const uint4 v = *reinterpret_cast<const uint4*>(hb + (size_t)s3 * IN_CH + c8 * 8);
            UNPACK_ADD(a3, v);
        }
    }

#define REDUCE_STORE(A, NN) do {                                        \
    _Pragma("unroll")                                                   \
    for (int j = 0; j < 8; ++j) {                                       \
        A[j] += __shfl_xor(A[j], 8);                                    \
        A[j] += __shfl_xor(A[j], 16);                                   \
        A[j] += __shfl_xor(A[j], 32);                                   \
    }                                                                   \
    if (sub == 0) {                                                     \
        const float inv = 1.0f / (float)((d_[NN] > 1) ? d_[NN] : 1);    \
        uint4 o;                                                        \
        _Pragma("unroll")                                               \
        for (int j = 0; j < 4; ++j) {                                   \
            const unsigned int l = f2bf(A[2 * j] * inv);                \
            const unsigned int hh = f2bf(A[2 * j + 1] * inv);           \
            (&o.x)[j] = l | (hh << 16);                                 \
        }                                                               \
        *reinterpret_cast<uint4*>(&s_mean[w * 4 + NN][c8 * 8]) = o;     \
    } } while (0)

    REDUCE_STORE(a0, 0);
    REDUCE_STORE(a1, 1);
    REDUCE_STORE(a2, 2);
    REDUCE_STORE(a3, 3);
#undef REDUCE_STORE

    __syncthreads();

    // ---- phase 2: MFMA; wave w handles col-tiles 2w, 2w+1 ----
    const int lrow = lane & 15;
    const int lk8 = (lane >> 4) * 8;

    bf16x8 a[4];
    a[0] = *reinterpret_cast<const bf16x8*>(&s_mean[lrow][lk8]);
    a[1] = *reinterpret_cast<const bf16x8*>(&s_mean[lrow][32 + lk8]);
    {
        const unsigned short* ah = hb + (size_t)perm[base + lrow] * IN_CH;
        a[2] = *reinterpret_cast<const bf16x8*>(ah + lk8);
        a[3] = *reinterpret_cast<const bf16x8*>(ah + 32 + lk8);
    }

#pragma unroll
    for (int c = 0; c < 2; ++c) {
        const int ct = 2 * w + c;
        f32x4 acc2 = (f32x4){0.f, 0.f, 0.f, 0.f};
#pragma unroll
        for (int kk = 0; kk < 4; ++kk) {
            const bf16x8 b = *reinterpret_cast<const bf16x8*>(
                Bt + (size_t)(ct * 16 + lrow) * 128 + kk * 32 + lk8);
            acc2 = __builtin_amdgcn_mfma_f32_16x16x32_bf16(a[kk], b, acc2, 0, 0, 0);
        }
        const int ch = ct * 16 + lrow;
        const float bv = bias[ch];
#pragma unroll
        for (int r = 0; r < 4; ++r) {
            const int node = perm[base + (lane >> 4) * 4 + r];
            out[(size_t)node * HID_CH + ch] = acc2[r] + bv;
        }
    }
}

// ---------------- fallback (old atomic path) ----------------

__global__ __launch_bounds__(256) void sage_scatter(
    const int* __restrict__ ei, const float* __restrict__ h,
    float* __restrict__ agg, float* __restrict__ deg)
{
    const int gtid = blockIdx.x * blockDim.x + threadIdx.x;
    const int edge = gtid >> 6;
    const int lane = threadIdx.x & 63;
    if (edge >= N_EDGES) return;
    const int dst = ei[edge];
    const int src = ei[N_EDGES + edge];
    atomicAdd(&agg[(size_t)dst * IN_CH + lane], h[(size_t)src * IN_CH + lane]);
    if (lane == 0) atomicAdd(&deg[dst], 1.0f);
}

__global__ __launch_bounds__(128) void sage_node(
    const float* __restrict__ h, const float* __restrict__ agg,
    const float* __restrict__ deg, const float* __restrict__ Wl,
    const float* __restrict__ bias, const float* __restrict__ Wr,
    float* __restrict__ out)
{
    const int t = threadIdx.x;
    float wl[IN_CH], wr[IN_CH];
#pragma unroll
    for (int k = 0; k < IN_CH; ++k) {
        wl[k] = Wl[k * HID_CH + t];
        wr[k] = Wr[k * HID_CH + t];
    }
    const float b = bias[t];
    __shared__ float s_mean[IN_CH];
    __shared__ float s_h[IN_CH];
    for (int n = blockIdx.x; n < N_NODES; n += gridDim.x) {
        __syncthreads();
        if (t < IN_CH) {
            const float inv = 1.0f / fmaxf(deg[n], 1.0f);
            s_mean[t] = agg[(size_t)n * IN_CH + t] * inv;
            s_h[t] = h[(size_t)n * IN_CH + t];
        }
        __syncthreads();
        float acc = b;
#pragma unroll
        for (int k = 0; k < IN_CH; ++k) {
            acc = fmaf(s_mean[k], wl[k], acc);
            acc = fmaf(s_h[k], wr[k], acc);
        }
        out[(size_t)n * HID_CH + t] = acc;
    }
}

extern "C" void kernel_launch(void* const* d_in, const int* in_sizes, int n_in,
                              void* d_out, int out_size, void* d_ws, size_t ws_size,
                              hipStream_t stream) {
    // inputs: 0=x (unused), 1=edge_index, 2=emb_weight, 3=lin_l_w, 4=lin_l_b, 5=lin_r_w
    const int* ei = (const int*)d_in[1];
    const float* h = (const float*)d_in[2];
    const float* Wl = (const float*)d_in[3];
    const float* b = (const float*)d_in[4];
    const float* Wr = (const float*)d_in[5];
    float* out = (float*)d_out;

    // ws layout (4B elements):
    //   node_cnt   [0,       100000)
    //   node_start [100000,  200000)
    //   bin_cursor [200000,  200391)   (zeroed)
    //   Bt         [200400,  208592)   (bf16 128x128 = 8192 dwords)
    //   perm       [210000,  310096)   (391 bins x 256 slots)
    //   bucket     [400000,  2301824)  (391 bins x 4864 cap)
    //   stage      [2400000, 4301824)  (391 bins x 4864 cap)
    //   hb         [4400000, 7600000)  (bf16 100000x64 = 3.2M dwords)
    const size_t need = 7600000ull * 4ull;

    if (ws_size >= need) {
        int* wsi = (int*)d_ws;
        int* node_cnt = wsi;
        int* node_start = wsi + 100000;
        int* bin_cursor = wsi + 200000;
        unsigned short* Bt = (unsigned short*)(wsi + 200400);
        int* perm = wsi + 210000;
        int* bucket = wsi + 400000;
        int* stage = wsi + 2400000;
        unsigned short* hb = (unsigned short*)(wsi + 4400000);

        hipMemsetAsync(bin_cursor, 0, NBINS * sizeof(int), stream);

        sage_stage<<<STAGE_BLOCKS, 256, 0, stream>>>(ei, bin_cursor, stage);
        sage_bucket2<<<NBINS + CVT_BLOCKS, 256, 0, stream>>>(
            stage, bin_cursor, Wl, Wr, h, hb, Bt, node_cnt, node_start, bucket, perm);
        sage_gmfma<<<N_NODES / 16, 256, 0, stream>>>(
            node_cnt, node_start, bucket, hb, Bt, b, perm, out);
    } else {
        // fallback: atomic scatter path
        float* agg = (float*)d_ws;
        float* deg = agg + (size_t)N_NODES * IN_CH;
        hipMemsetAsync(d_ws, 0, ((size_t)N_NODES * IN_CH + N_NODES) * sizeof(float), stream);
        sage_scatter<<<(int)(((long long)N_EDGES * 64 + 255) / 256), 256, 0, stream>>>(ei, h, agg, deg);
        sage_node<<<4096, 128, 0, stream>>>(h, agg, deg, Wl, b, Wr, out);
    }
}

// Round 27
// 122.405 us; speedup vs baseline: 1.0516x; 1.0516x over previous
//
#include <hip/hip_runtime.h>

#define N_NODES 100000
#define N_EDGES 1600000
#define IN_CH 64
#define HID_CH 128

#define BIN_SZ 256                                     // nodes per bin
#define BIN_BITS 8
#define NBINS ((N_NODES + BIN_SZ - 1) / BIN_SZ)        // 391 bins
#define BIN_CAP 4864                                   // fixed region per bin
#define SEPB 4096                                      // edges per stage block
#define STAGE_BLOCKS ((N_EDGES + SEPB - 1) / SEPB)     // 391
#define EPT 16                                         // edges per thread (SEPB/256)
#define CVT_BLOCKS 768                                 // dedicated h->bf16 blocks
#define BIN_CACHE 8192                                 // LDS edge cache per bin

typedef __attribute__((ext_vector_type(8))) short bf16x8;  // 8 bf16 = 4 VGPR
typedef __attribute__((ext_vector_type(4))) float f32x4;

static __device__ __forceinline__ unsigned short f2bf(float f) {
    union { float f; unsigned int u; } v; v.f = f;
    const unsigned int u = v.u;
    return (unsigned short)((u + 0x7FFFu + ((u >> 16) & 1u)) >> 16);  // RNE
}

#define UNPACK_ADD(A, V) do {                                         \
    union { unsigned int u; float f; } lo_, hi_;                      \
    _Pragma("unroll")                                                 \
    for (int j_ = 0; j_ < 4; ++j_) {                                  \
        const unsigned int w_ = (&(V).x)[j_];                         \
        lo_.u = w_ << 16;         A[2 * j_] += lo_.f;                 \
        hi_.u = w_ & 0xFFFF0000u; A[2 * j_ + 1] += hi_.f;             \
    } } while (0)

// ---------------- stage: histogram-free partition, single ei read ---------
// Fixed-capacity bin regions (bin b at [b*BIN_CAP, (b+1)*BIN_CAP)); each
// block reserves per-bin runs directly from bin_cursor. Edges are read ONCE
// and retained in registers (16/thread) across the count and scatter passes.
__global__ __launch_bounds__(256) void sage_stage(
    const int* __restrict__ ei, int* __restrict__ bin_cursor,
    int* __restrict__ stage)
{
    __shared__ int s_cnt[NBINS];
    __shared__ int s_base[NBINS];
    const int t = threadIdx.x;
    for (int i = t; i < NBINS; i += 256) s_cnt[i] = 0;
    __syncthreads();
    const int e0 = blockIdx.x * SEPB;
    int pk[EPT];
    short bin[EPT];
#pragma unroll
    for (int k = 0; k < EPT; ++k) {
        const int e = e0 + k * 256 + t;
        if (e < N_EDGES) {
            const int dst = ei[e];
            const int src = ei[N_EDGES + e];
            bin[k] = (short)(dst >> BIN_BITS);
            pk[k] = ((dst & (BIN_SZ - 1)) << 17) | src;
            atomicAdd(&s_cnt[bin[k]], 1);
        } else bin[k] = -1;
    }
    __syncthreads();
    // reserve one run per bin at fixed base bin*BIN_CAP
    for (int i = t; i < NBINS; i += 256) {
        const int c = s_cnt[i];
        s_base[i] = (c > 0) ? (i * BIN_CAP + atomicAdd(&bin_cursor[i], c)) : 0;
        s_cnt[i] = 0;
    }
    __syncthreads();
    // scatter from registers (clamped to bin region; never triggers here)
#pragma unroll
    for (int k = 0; k < EPT; ++k) {
        if (bin[k] >= 0) {
            const int bb = bin[k];
            const int p = s_base[bb] + atomicAdd(&s_cnt[bb], 1);
            if (p < (bb + 1) * BIN_CAP)
                stage[p] = pk[k];
        }
    }
}

// ---------------- bucket2: per-bin CSR finalize + fused cvt_w + cvt_h -----
__global__ __launch_bounds__(256) void sage_bucket2(
    const int* __restrict__ stage, const int* __restrict__ bin_cursor,
    const float* __restrict__ Wl, const float* __restrict__ Wr,
    const float* __restrict__ h, unsigned short* __restrict__ hb,
    unsigned short* __restrict__ Bt, int* __restrict__ node_cnt,
    int* __restrict__ node_start, int* __restrict__ bucket)
{
    const int b = blockIdx.x;
    const int t = threadIdx.x;

    if (b >= NBINS) {
        // dedicated h -> bf16 conversion blocks (concurrent with bin work)
        const int n4 = N_NODES * IN_CH / 4;
        for (int i = (b - NBINS) * 256 + t; i < n4; i += CVT_BLOCKS * 256) {
            const float4 v = reinterpret_cast<const float4*>(h)[i];
            ushort4 o;
            o.x = f2bf(v.x); o.y = f2bf(v.y); o.z = f2bf(v.z); o.w = f2bf(v.w);
            reinterpret_cast<ushort4*>(hb)[i] = o;
        }
        return;
    }

    __shared__ int s_cnt[BIN_SZ];
    __shared__ int s_off[BIN_SZ];
    __shared__ int s_cur[BIN_SZ];
    __shared__ int s_edges[BIN_CACHE];
    // fused Bt pack: first 64 blocks cover 128x128
    {
        const int wi = b * 256 + t;
        if (wi < HID_CH * HID_CH) {
            const int n = wi >> 7, k = wi & 127;
            const float v = (k < 64) ? Wl[k * HID_CH + n] : Wr[(k - 64) * HID_CH + n];
            Bt[wi] = f2bf(v);
        }
    }
    s_cnt[t] = 0; s_cur[t] = 0;
    __syncthreads();
    const int start = b * BIN_CAP;
    int len = bin_cursor[b];
    len = (len > BIN_CAP) ? BIN_CAP : len;
    const bool cached = (len <= BIN_CACHE);
    if (cached) {
        for (int i = t; i < len; i += 256) {
            const int p = stage[start + i];
            s_edges[i] = p;
            atomicAdd(&s_cnt[p >> 17], 1);
        }
    } else {
        for (int i = t; i < len; i += 256)
            atomicAdd(&s_cnt[stage[start + i] >> 17], 1);
    }
    __syncthreads();
    const int v = s_cnt[t];
    s_off[t] = v;
    __syncthreads();
    for (int off = 1; off < 256; off <<= 1) {
        const int a = (t >= off) ? s_off[t - off] : 0;
        __syncthreads();
        s_off[t] += a;
        __syncthreads();
    }
    const int excl = s_off[t] - v;
    s_off[t] = excl;
    __syncthreads();
    const int node = (b << BIN_BITS) + t;
    if (node < N_NODES) {
        node_cnt[node] = v;
        node_start[node] = start + excl;
    }
    if (cached) {
        for (int i = t; i < len; i += 256) {
            const int p = s_edges[i];
            const int l = p >> 17;
            bucket[start + s_off[l] + atomicAdd(&s_cur[l], 1)] = p & 0x1FFFF;
        }
    } else {
        for (int i = t; i < len; i += 256) {
            const int p = stage[start + i];
            const int l = p >> 17;
            bucket[start + s_off[l] + atomicAdd(&s_cur[l], 1)] = p & 0x1FFFF;
        }
    }
}

// ---------------- fused gather+mean+MFMA (round-12 best variant) ----------
// One block = 16 nodes = one m-tile, 256 threads = 4 waves. Phase 1: each
// wave gathers its 4 nodes INTERLEAVED (4 idx->row chains in flight) -> bf16
// means to LDS. Phase 2: each wave computes 2 col-tiles (4 MFMA each).
// NOTE: 9 structural variants tested (rounds 9-26); this one is the floor
// (74.7-75.2 us, VGPR 36, ~62% occupancy). TLP >> in-wave ILP; any node
// permutation (degree sort) costs more in lost hb/out locality than it
// saves in maxd tail (rounds 16, 26).
__global__ __launch_bounds__(256) void sage_gmfma(
    const int* __restrict__ node_cnt, const int* __restrict__ node_start,
    const int* __restrict__ bucket, const unsigned short* __restrict__ hb,
    const unsigned short* __restrict__ Bt, const float* __restrict__ bias,
    float* __restrict__ out)
{
    __shared__ unsigned short s_mean[16][72];  // padded: 144B row stride
    const int t = threadIdx.x;
    const int w = t >> 6;           // wave 0..3
    const int lane = t & 63;
    const int sub = lane >> 3;      // edge slot 0..7
    const int c8 = lane & 7;        // 8-channel group within row
    const int node0 = blockIdx.x * 16;

    // ---- phase 1: interleaved gather for the wave's 4 nodes ----
    int d_[4], st_[4];
#pragma unroll
    for (int nn = 0; nn < 4; ++nn) {
        const int node = node0 + w * 4 + nn;
        d_[nn] = node_cnt[node];
        st_[nn] = node_start[node];
    }
    int maxd = d_[0];
#pragma unroll
    for (int nn = 1; nn < 4; ++nn) maxd = (d_[nn] > maxd) ? d_[nn] : maxd;

    float a0[8] = {0.f,0.f,0.f,0.f,0.f,0.f,0.f,0.f};
    float a1[8] = {0.f,0.f,0.f,0.f,0.f,0.f,0.f,0.f};
    float a2[8] = {0.f,0.f,0.f,0.f,0.f,0.f,0.f,0.f};
    float a3[8] = {0.f,0.f,0.f,0.f,0.f,0.f,0.f,0.f};

    for (int g = 0; g < maxd; g += 8) {
        const int e = g + sub;
        int s0 = -1, s1 = -1, s2 = -1, s3 = -1;
        if (e < d_[0]) s0 = bucket[st_[0] + e];
        if (e < d_[1]) s1 = bucket[st_[1] + e];
        if (e < d_[2]) s2 = bucket[st_[2] + e];
        if (e < d_[3]) s3 = bucket[st_[3] + e];
        if (s0 >= 0) {
            const uint4 v = *reinterpret_cast<const uint4*>(hb + (size_t)s0 * IN_CH + c8 * 8);
            UNPACK_ADD(a0, v);
        }
        if (s1 >= 0) {
            const uint4 v = *reinterpret_cast<const uint4*>(hb + (size_t)s1 * IN_CH + c8 * 8);
            UNPACK_ADD(a1, v);
        }
        if (s2 >= 0) {
            const uint4 v = *reinterpret_cast<const uint4*>(hb + (size_t)s2 * IN_CH + c8 * 8);
            UNPACK_ADD(a2, v);
        }
        if (s3 >= 0) {
            const uint4 v = *reinterpret_cast<const uint4*>(hb + (size_t)s3 * IN_CH + c8 * 8);
            UNPACK_ADD(a3, v);
        }
    }

#define REDUCE_STORE(A, NN) do {                                        \
    _Pragma("unroll")                                                   \
    for (int j = 0; j < 8; ++j) {                                       \
        A[j] += __shfl_xor(A[j], 8);                                    \
        A[j] += __shfl_xor(A[j], 16);                                   \
        A[j] += __shfl_xor(A[j], 32);                                   \
    }                                                                   \
    if (sub == 0) {                                                     \
        const float inv = 1.0f / (float)((d_[NN] > 1) ? d_[NN] : 1);    \
        uint4 o;                                                        \
        _Pragma("unroll")                                               \
        for (int j = 0; j < 4; ++j) {                                   \
            const unsigned int l = f2bf(A[2 * j] * inv);                \
            const unsigned int hh = f2bf(A[2 * j + 1] * inv);           \
            (&o.x)[j] = l | (hh << 16);                                 \
        }                                                               \
        *reinterpret_cast<uint4*>(&s_mean[w * 4 + NN][c8 * 8]) = o;     \
    } } while (0)

    REDUCE_STORE(a0, 0);
    REDUCE_STORE(a1, 1);
    REDUCE_STORE(a2, 2);
    REDUCE_STORE(a3, 3);
#undef REDUCE_STORE

    __syncthreads();

    // ---- phase 2: MFMA; wave w handles col-tiles 2w, 2w+1 ----
    const int lrow = lane & 15;
    const int lk8 = (lane >> 4) * 8;

    bf16x8 a[4];
    a[0] = *reinterpret_cast<const bf16x8*>(&s_mean[lrow][lk8]);
    a[1] = *reinterpret_cast<const bf16x8*>(&s_mean[lrow][32 + lk8]);
    {
        const unsigned short* ah = hb + (size_t)(node0 + lrow) * IN_CH;
        a[2] = *reinterpret_cast<const bf16x8*>(ah + lk8);
        a[3] = *reinterpret_cast<const bf16x8*>(ah + 32 + lk8);
    }

#pragma unroll
    for (int c = 0; c < 2; ++c) {
        const int ct = 2 * w + c;
        f32x4 acc2 = (f32x4){0.f, 0.f, 0.f, 0.f};
#pragma unroll
        for (int kk = 0; kk < 4; ++kk) {
            const bf16x8 b = *reinterpret_cast<const bf16x8*>(
                Bt + (size_t)(ct * 16 + lrow) * 128 + kk * 32 + lk8);
            acc2 = __builtin_amdgcn_mfma_f32_16x16x32_bf16(a[kk], b, acc2, 0, 0, 0);
        }
        const int ch = ct * 16 + lrow;
        const float bv = bias[ch];
#pragma unroll
        for (int r = 0; r < 4; ++r) {
            const int node = node0 + (lane >> 4) * 4 + r;
            out[(size_t)node * HID_CH + ch] = acc2[r] + bv;
        }
    }
}

// ---------------- fallback (old atomic path) ----------------

__global__ __launch_bounds__(256) void sage_scatter(
    const int* __restrict__ ei, const float* __restrict__ h,
    float* __restrict__ agg, float* __restrict__ deg)
{
    const int gtid = blockIdx.x * blockDim.x + threadIdx.x;
    const int edge = gtid >> 6;
    const int lane = threadIdx.x & 63;
    if (edge >= N_EDGES) return;
    const int dst = ei[edge];
    const int src = ei[N_EDGES + edge];
    atomicAdd(&agg[(size_t)dst * IN_CH + lane], h[(size_t)src * IN_CH + lane]);
    if (lane == 0) atomicAdd(&deg[dst], 1.0f);
}

__global__ __launch_bounds__(128) void sage_node(
    const float* __restrict__ h, const float* __restrict__ agg,
    const float* __restrict__ deg, const float* __restrict__ Wl,
    const float* __restrict__ bias, const float* __restrict__ Wr,
    float* __restrict__ out)
{
    const int t = threadIdx.x;
    float wl[IN_CH], wr[IN_CH];
#pragma unroll
    for (int k = 0; k < IN_CH; ++k) {
        wl[k] = Wl[k * HID_CH + t];
        wr[k] = Wr[k * HID_CH + t];
    }
    const float b = bias[t];
    __shared__ float s_mean[IN_CH];
    __shared__ float s_h[IN_CH];
    for (int n = blockIdx.x; n < N_NODES; n += gridDim.x) {
        __syncthreads();
        if (t < IN_CH) {
            const float inv = 1.0f / fmaxf(deg[n], 1.0f);
            s_mean[t] = agg[(size_t)n * IN_CH + t] * inv;
            s_h[t] = h[(size_t)n * IN_CH + t];
        }
        __syncthreads();
        float acc = b;
#pragma unroll
        for (int k = 0; k < IN_CH; ++k) {
            acc = fmaf(s_mean[k], wl[k], acc);
            acc = fmaf(s_h[k], wr[k], acc);
        }
        out[(size_t)n * HID_CH + t] = acc;
    }
}

extern "C" void kernel_launch(void* const* d_in, const int* in_sizes, int n_in,
                              void* d_out, int out_size, void* d_ws, size_t ws_size,
                              hipStream_t stream) {
    // inputs: 0=x (unused), 1=edge_index, 2=emb_weight, 3=lin_l_w, 4=lin_l_b, 5=lin_r_w
    const int* ei = (const int*)d_in[1];
    const float* h = (const float*)d_in[2];
    const float* Wl = (const float*)d_in[3];
    const float* b = (const float*)d_in[4];
    const float* Wr = (const float*)d_in[5];
    float* out = (float*)d_out;

    // ws layout (4B elements):
    //   node_cnt   [0,       100000)
    //   node_start [100000,  200000)
    //   bin_cursor [200000,  200391)   (zeroed)
    //   Bt         [200400,  208592)   (bf16 128x128 = 8192 dwords)
    //   bucket     [400000,  2301824)  (391 bins x 4864 cap)
    //   stage      [2400000, 4301824)  (391 bins x 4864 cap)
    //   hb         [4400000, 7600000)  (bf16 100000x64 = 3.2M dwords)
    const size_t need = 7600000ull * 4ull;

    if (ws_size >= need) {
        int* wsi = (int*)d_ws;
        int* node_cnt = wsi;
        int* node_start = wsi + 100000;
        int* bin_cursor = wsi + 200000;
        unsigned short* Bt = (unsigned short*)(wsi + 200400);
        int* bucket = wsi + 400000;
        int* stage = wsi + 2400000;
        unsigned short* hb = (unsigned short*)(wsi + 4400000);

        hipMemsetAsync(bin_cursor, 0, NBINS * sizeof(int), stream);

        sage_stage<<<STAGE_BLOCKS, 256, 0, stream>>>(ei, bin_cursor, stage);
        sage_bucket2<<<NBINS + CVT_BLOCKS, 256, 0, stream>>>(
            stage, bin_cursor, Wl, Wr, h, hb, Bt, node_cnt, node_start, bucket);
        sage_gmfma<<<N_NODES / 16, 256, 0, stream>>>(node_cnt, node_start, bucket, hb, Bt, b, out);
    } else {
        // fallback: atomic scatter path
        float* agg = (float*)d_ws;
        float* deg = agg + (size_t)N_NODES * IN_CH;
        hipMemsetAsync(d_ws, 0, ((size_t)N_NODES * IN_CH + N_NODES) * sizeof(float), stream);
        sage_scatter<<<(int)(((long long)N_EDGES * 64 + 255) / 256), 256, 0, stream>>>(ei, h, agg, deg);
        sage_node<<<4096, 128, 0, stream>>>(h, agg, deg, Wl, b, Wr, out);
    }
}